// Round 7
// baseline (119.690 us; speedup 1.0000x reference)
//
#include <hip/hip_runtime.h>
#include <hip/hip_bf16.h>
#include <math.h>

#define BB 4
#define NN 2046
#define IND 512
#define DD 1024
#define SS 2048
#define MM (BB*NN)          // 8184 real rows, padded to 8192
#define MPAD 8192
#define RPAD 8256
#define EPSV 1e-5f

// ---- ws float offsets ----
#define F_U      0          // [2][1024] u-vectors
#define F_G      2048       // [32]
#define F_C2     2080       // [32]
#define F_SSPEC  2112       // [2][2] special-row s1,s2
#define F_DEN    2116       // [128] softmax denominators
#define F_S12    4096       // [8192][8 nb][2] per-ntile S1,S2 partials
#define F_A      135168     // [32][RPAD] A-values (specials at MPAD+p)
// ---- ws byte offsets ----
#define B_XH   1597440      // bf16[8192][512]   x hi
#define B_WHT  9986048      // bf16[1024][512]   W^T hi
#define B_WLT  11034624     // bf16[1024][512]   W^T lo

typedef float f32x4 __attribute__((ext_vector_type(4)));
typedef __bf16 bf16x8 __attribute__((ext_vector_type(8)));
typedef unsigned short u16x8 __attribute__((ext_vector_type(8)));

__device__ __forceinline__ unsigned short f2bf_rne(float f) {
  unsigned int u = __float_as_uint(f);
  u += 0x7FFFu + ((u >> 16) & 1u);
  return (unsigned short)(u >> 16);
}
__device__ __forceinline__ float bf2f(unsigned short h) {
  return __uint_as_float(((unsigned int)h) << 16);
}
__device__ __forceinline__ float waveSum(float v) {
  #pragma unroll
  for (int m = 32; m >= 1; m >>= 1) v += __shfl_xor(v, m, 64);
  return v;
}
__device__ __forceinline__ float blockReduceSum(float v, volatile float* buf4) {
  #pragma unroll
  for (int m = 32; m >= 1; m >>= 1) v += __shfl_xor(v, m, 64);
  int wid = threadIdx.x >> 6;
  __syncthreads();
  if ((threadIdx.x & 63) == 0) buf4[wid] = v;
  __syncthreads();
  return buf4[0] + buf4[1] + buf4[2] + buf4[3];
}

#define GLOAD_LDS16(g, l) \
  __builtin_amdgcn_global_load_lds((const __attribute__((address_space(1))) void*)(g), \
                                   (__attribute__((address_space(3))) void*)(l), 16, 0, 0)

// ---------------------------------------------------------------------------
// prep: convX (x->xh bf16 hi, rows padded to 8192) | convW (W -> transposed
// hi/lo bf16 [1024][512]) | stageA (LN consts, u, G, C2, special-row S/A)
// ---------------------------------------------------------------------------
__global__ __launch_bounds__(256) void prep(
    const float* __restrict__ x, const float* __restrict__ Wm,
    const float* __restrict__ tt, const float* __restrict__ ct,
    const float* __restrict__ lng, const float* __restrict__ lnb,
    const float* __restrict__ Wq, const float* __restrict__ bq,
    const float* __restrict__ Wk, const float* __restrict__ bk,
    unsigned short* __restrict__ xh, unsigned short* __restrict__ wht,
    unsigned short* __restrict__ wlt, float* __restrict__ ws) {
  __shared__ float tile[64][65];
  __shared__ float hq[4][64];
  __shared__ float qs[4][64];
  const int bid = blockIdx.x, t = threadIdx.x;

  if (bid < 2048) {                     // ---- convX ----
    const int row = bid * 4 + (t >> 6);
    const int c0 = (t & 63) * 8;
    const size_t po = (size_t)row * IND + c0;
    u16x8 hv;
    if (row < MM) {
      const float4* xv = (const float4*)(x + po);
      float4 a = xv[0], b = xv[1];
      float vv[8] = {a.x, a.y, a.z, a.w, b.x, b.y, b.z, b.w};
      #pragma unroll
      for (int i = 0; i < 8; ++i) hv[i] = f2bf_rne(vv[i]);
    } else {
      #pragma unroll
      for (int i = 0; i < 8; ++i) hv[i] = 0;
    }
    *(u16x8*)(xh + po) = hv;
  } else if (bid < 2176) {              // ---- convW: transpose + hi/lo ----
    const int b2 = bid - 2048;
    const int kb = b2 >> 4, nb = b2 & 15;
    const int k0 = kb * 64, n0 = nb * 64;
    #pragma unroll
    for (int q = 0; q < 16; ++q) {
      int lin = q * 256 + t;
      int kk = lin >> 6, nn = lin & 63;
      tile[kk][nn] = Wm[(size_t)(k0 + kk) * DD + n0 + nn];
    }
    __syncthreads();
    #pragma unroll
    for (int q = 0; q < 16; ++q) {
      int lin = q * 256 + t;
      int nn = lin >> 6, kk = lin & 63;
      float v = tile[kk][nn];
      unsigned short hh = f2bf_rne(v);
      wht[(size_t)(n0 + nn) * IND + k0 + kk] = hh;
      wlt[(size_t)(n0 + nn) * IND + k0 + kk] = f2bf_rne(v - bf2f(hh));
    }
  } else {                              // ---- stageA: one (s,h) per wave ----
    const int w = t >> 6, e = t & 63;
    const int sh = (bid - 2176) * 4 + w;
    const int s = sh >> 4, h = sh & 15;
    const float* src = s ? ct : tt;

    float s1 = 0.f, s2 = 0.f;
    #pragma unroll
    for (int i = 0; i < 16; ++i) { float v = src[i*64 + e]; s1 += v; s2 += v*v; }
    s1 = waveSum(s1); s2 = waveSum(s2);
    if (h == 0 && e == 0) {
      ws[F_SSPEC + s*2 + 0] = s1;
      ws[F_SSPEC + s*2 + 1] = s2;
    }
    const float mu = s1 * (1.f/DD);
    const float var = s2 * (1.f/DD) - mu*mu;
    const float rstd = rsqrtf(var + EPSV);
    const int d0 = h * 64;
    hq[w][e] = (src[d0+e] - mu) * rstd * lng[d0+e] + lnb[d0+e];
    float qv = bq[d0+e];
    #pragma unroll 8
    for (int d = 0; d < 64; ++d) qv += hq[w][d] * Wq[(size_t)(d0+d)*64 + e];
    qs[w][e] = qv;
    float wt = 0.f;
    #pragma unroll 8
    for (int ee = 0; ee < 64; ++ee) wt += Wk[(size_t)(d0+e)*64 + ee] * qs[w][ee];
    wt *= 0.125f;
    const float c = waveSum(qs[w][e] * bk[d0+e]) * 0.125f;
    const float u = lng[d0+e] * wt;
    ws[F_U + s*DD + d0 + e] = u;
    const float G  = waveSum(lng[d0+e] * wt);
    const float C  = waveSum(lnb[d0+e] * wt);
    const float a0 = waveSum(tt[d0+e] * u);
    const float a1 = waveSum(ct[d0+e] * u);
    if (e == 0) {
      ws[F_G  + sh] = G;
      ws[F_C2 + sh] = C + c;
      ws[F_A + (size_t)sh*RPAD + MPAD + 0] = a0;
      ws[F_A + (size_t)sh*RPAD + MPAD + 1] = a1;
    }
  }
}

// ---------------------------------------------------------------------------
// stageB: token GEMM xh[8192][512] @ W^T hi/lo (2-product split-bf16),
// 128x128 tiles, BK=32 double-buffered global_load_lds pipeline with counted
// vmcnt(6). RACE FIX (R7): sched_barrier(0) fences pin every phase edge so
// MFMAs (register-only; hipcc may move them across asm memory clobbers,
// rule #18) cannot sink past the phase-closing s_barrier; explicit
// lgkmcnt(0) guarantees all ds_reads drained before the barrier signals.
// Fused epilogue: per-row S1/S2 partials + per-(query,head) A, zero atomics.
// bid = nb*64 + mb (the 8 nb-tiles sharing an mb row-panel land on one XCD).
// ---------------------------------------------------------------------------
__global__ __launch_bounds__(256, 2) void stageB(
    const unsigned short* __restrict__ xh,
    const unsigned short* __restrict__ wht, const unsigned short* __restrict__ wlt,
    const float* __restrict__ bmap, float* __restrict__ ws) {
  __shared__ char smem[49152];  // A: [2][128][32]bf16 @0; B h/l: [2][2][128][32] @16384
  const int t = threadIdx.x, wave = t >> 6, lane = t & 63;
  const int lj = lane & 15, lg = lane >> 4;
  const int mb = blockIdx.x & 63, nb = blockIdx.x >> 6;
  const int m0 = mb * 128, n0 = nb * 128;
  const int wr = wave >> 1, wc = wave & 1;
  const float* U = ws + F_U;

  f32x4 acc[4][4];
  #pragma unroll
  for (int i = 0; i < 4; ++i)
    #pragma unroll
    for (int j = 0; j < 4; ++j) acc[i][j] = (f32x4){0.f,0.f,0.f,0.f};

  const int srow = lane >> 2;                 // 0..15: row within 16-row group
  const int gslot = (lane & 3) ^ (srow & 3);  // pre-swizzled global 16B slot

  #define STAGE(ks, buf) do {                                                  \
    const size_t ko_ = (size_t)(ks)*32 + gslot*8;                              \
    _Pragma("unroll")                                                          \
    for (int q = 0; q < 2; ++q) {                                              \
      const int rb = wave*32 + q*16;                                           \
      GLOAD_LDS16(xh  + (size_t)(m0 + rb + srow)*IND + ko_,                    \
                  smem + (buf)*8192 + rb*64);                                  \
      GLOAD_LDS16(wht + (size_t)(n0 + rb + srow)*IND + ko_,                    \
                  smem + 16384 + (buf)*16384 + rb*64);                         \
      GLOAD_LDS16(wlt + (size_t)(n0 + rb + srow)*IND + ko_,                    \
                  smem + 16384 + (buf)*16384 + 8192 + rb*64);                  \
    }                                                                          \
  } while (0)

  STAGE(0, 0);
  #pragma unroll
  for (int k = 0; k < 16; ++k) {
    if (k < 15) {
      STAGE(k + 1, (k + 1) & 1);
      asm volatile("s_waitcnt vmcnt(6)" ::: "memory");
    } else {
      asm volatile("s_waitcnt vmcnt(0)" ::: "memory");
    }
    __builtin_amdgcn_sched_barrier(0);
    __builtin_amdgcn_s_barrier();
    __builtin_amdgcn_sched_barrier(0);
    {
      const int ab = (k & 1) * 8192;
      const int bb = 16384 + (k & 1) * 16384;
      bf16x8 af[4], bfh[4], bfl[4];
      #pragma unroll
      for (int i = 0; i < 4; ++i) {
        const int r = wr*64 + i*16 + lj;
        af[i] = *(const bf16x8*)(smem + ab + r*64 + ((lg ^ (r & 3)) * 16));
      }
      #pragma unroll
      for (int j = 0; j < 4; ++j) {
        const int r = wc*64 + j*16 + lj;
        const int byt = r*64 + ((lg ^ (r & 3)) * 16);
        bfh[j] = *(const bf16x8*)(smem + bb + byt);
        bfl[j] = *(const bf16x8*)(smem + bb + 8192 + byt);
      }
      #pragma unroll
      for (int i = 0; i < 4; ++i)
        #pragma unroll
        for (int j = 0; j < 4; ++j) {
          acc[i][j] = __builtin_amdgcn_mfma_f32_16x16x32_bf16(af[i], bfh[j], acc[i][j], 0,0,0);
          acc[i][j] = __builtin_amdgcn_mfma_f32_16x16x32_bf16(af[i], bfl[j], acc[i][j], 0,0,0);
        }
    }
    __builtin_amdgcn_sched_barrier(0);
    asm volatile("s_waitcnt lgkmcnt(0)" ::: "memory");
    __builtin_amdgcn_sched_barrier(0);
    __builtin_amdgcn_s_barrier();
    __builtin_amdgcn_sched_barrier(0);
  }
  #undef STAGE

  // ---- fused epilogue: per-row S1,S2 and per-(query,head) A ----
  float s1p[16], s2p[16], a0p[16], a1p[16];
  #pragma unroll
  for (int p = 0; p < 16; ++p) { s1p[p]=0.f; s2p[p]=0.f; a0p[p]=0.f; a1p[p]=0.f; }
  #pragma unroll
  for (int j = 0; j < 4; ++j) {
    const int gc = n0 + wc*64 + j*16 + lj;
    const float bmv = bmap[gc];
    const float u0 = U[gc], u1 = U[DD + gc];
    #pragma unroll
    for (int i = 0; i < 4; ++i)
      #pragma unroll
      for (int r = 0; r < 4; ++r) {
        const float tok = acc[i][j][r] + bmv;
        const int p = i*4 + r;
        s1p[p] += tok; s2p[p] += tok*tok;
        a0p[p] += tok*u0; a1p[p] += tok*u1;
      }
  }
  #pragma unroll
  for (int msk = 8; msk >= 1; msk >>= 1)
    #pragma unroll
    for (int p = 0; p < 16; ++p) {
      s1p[p] += __shfl_xor(s1p[p], msk, 64);
      s2p[p] += __shfl_xor(s2p[p], msk, 64);
      a0p[p] += __shfl_xor(a0p[p], msk, 64);
      a1p[p] += __shfl_xor(a1p[p], msk, 64);
    }

  if (lj == 0) {
    const int h = nb*2 + wc;            // head owned by this wave's col-half
    #pragma unroll
    for (int p = 0; p < 16; ++p) {
      const int row = m0 + wr*64 + (p>>2)*16 + lg*4 + (p&3);
      ws[F_A + (size_t)h*RPAD + row]        = a0p[p];
      ws[F_A + (size_t)(16 + h)*RPAD + row] = a1p[p];
    }
  }

  float* s12w = (float*)smem;           // reuse staging LDS: [4][64][2]
  if (lj == 0) {
    #pragma unroll
    for (int p = 0; p < 16; ++p) {
      const int rl = (p>>2)*16 + lg*4 + (p&3);
      s12w[(wave*64 + rl)*2 + 0] = s1p[p];
      s12w[(wave*64 + rl)*2 + 1] = s2p[p];
    }
  }
  __syncthreads();
  if (t < 128) {
    const int wv = t >> 6, rl = t & 63;
    const float s1 = s12w[((wv*2)*64 + rl)*2]     + s12w[((wv*2+1)*64 + rl)*2];
    const float s2 = s12w[((wv*2)*64 + rl)*2 + 1] + s12w[((wv*2+1)*64 + rl)*2 + 1];
    ws[F_S12 + (size_t)(m0 + t)*16 + nb*2 + 0] = s1;
    ws[F_S12 + (size_t)(m0 + t)*16 + nb*2 + 1] = s2;
  }
}

// ---------------------------------------------------------------------------
// moments: sum the 8 per-ntile partials (regular rows); specials from SSPEC
// ---------------------------------------------------------------------------
__device__ __forceinline__ void rowMoments(const float* __restrict__ ws, int p,
                                           int r, float& mu, float& rstd) {
  float s1, s2;
  if (p < 2) {
    s1 = ws[F_SSPEC + p*2 + 0];
    s2 = ws[F_SSPEC + p*2 + 1];
  } else {
    const float4* q4 = (const float4*)(ws + F_S12 + (size_t)r*16);
    const float4 a = q4[0], b = q4[1], c = q4[2], d = q4[3];
    s1 = (a.x + a.z) + (b.x + b.z) + (c.x + c.z) + (d.x + d.z);
    s2 = (a.y + a.w) + (b.y + b.w) + (c.y + c.w) + (d.y + d.w);
  }
  mu = s1 * (1.f/DD);
  const float var = s2 * (1.f/DD) - mu*mu;
  rstd = rsqrtf(var + EPSV);
}

// ---------------------------------------------------------------------------
// stageC1: per (b,s,h) softmax denominator
// ---------------------------------------------------------------------------
__global__ __launch_bounds__(256) void stageC1(float* __restrict__ ws) {
  __shared__ float rbuf[4];
  const int bid = blockIdx.x;           // b*32 + s*16 + h
  const int b = bid >> 5, sh = bid & 31;
  const int t = threadIdx.x;
  const float Gh = ws[F_G + sh], Ch = ws[F_C2 + sh];
  const float* Af = ws + F_A + (size_t)sh*RPAD;

  float sum = 0.f;
  #pragma unroll
  for (int i = 0; i < 8; ++i) {
    const int p = i*256 + t;
    const int r = (p < 2) ? (MPAD + p) : (b*NN + p - 2);
    float mu, rstd;
    rowMoments(ws, p, r, mu, rstd);
    const float sc = fminf(rstd*(Af[r] - mu*Gh) + Ch, 60.f);
    sum += __expf(sc);
  }
  sum = blockReduceSum(sum, rbuf);
  if (t == 0) ws[F_DEN + bid] = sum;
}

// ---------------------------------------------------------------------------
// stageC2: output = mean over heads of per-head softmax probs
// ---------------------------------------------------------------------------
__global__ __launch_bounds__(256) void stageC2(const float* __restrict__ ws,
                                               float* __restrict__ out) {
  __shared__ float dn[16], Gs[16], Cs[16];
  const int bid = blockIdx.x;           // (b*2+s)*8 + chunk
  const int bs = bid >> 3, chunk = bid & 7;
  const int b = bs >> 1, s = bs & 1;
  const int t = threadIdx.x;
  if (t < 16) {
    dn[t] = 1.f / ws[F_DEN + b*32 + s*16 + t];
    Gs[t] = ws[F_G  + s*16 + t];
    Cs[t] = ws[F_C2 + s*16 + t];
  }
  __syncthreads();
  const int p = chunk*256 + t;
  const int r = (p < 2) ? (MPAD + p) : (b*NN + p - 2);
  float mu, rstd;
  rowMoments(ws, p, r, mu, rstd);
  float acc = 0.f;
  #pragma unroll
  for (int h = 0; h < 16; ++h) {
    const float a = ws[F_A + (size_t)(s*16 + h)*RPAD + r];
    const float sc = fminf(rstd*(a - mu*Gs[h]) + Cs[h], 60.f);
    acc += __expf(sc) * dn[h];
  }
  out[(size_t)s*(BB*SS) + (size_t)b*SS + p] = acc * (1.f/16.f);
}

extern "C" void kernel_launch(void* const* d_in, const int* in_sizes, int n_in,
                              void* d_out, int out_size, void* d_ws, size_t ws_size,
                              hipStream_t stream) {
  const float* x   = (const float*)d_in[0];
  const float* Wm  = (const float*)d_in[1];
  const float* bm  = (const float*)d_in[2];
  const float* tt  = (const float*)d_in[3];
  const float* ct  = (const float*)d_in[4];
  const float* lng = (const float*)d_in[5];
  const float* lnb = (const float*)d_in[6];
  const float* Wq  = (const float*)d_in[7];
  const float* bq  = (const float*)d_in[8];
  const float* Wk  = (const float*)d_in[9];
  const float* bk  = (const float*)d_in[10];
  char* wsb = (char*)d_ws;
  float* ws = (float*)d_ws;
  float* out = (float*)d_out;

  unsigned short* xh  = (unsigned short*)(wsb + B_XH);
  unsigned short* wht = (unsigned short*)(wsb + B_WHT);
  unsigned short* wlt = (unsigned short*)(wsb + B_WLT);

  hipLaunchKernelGGL(prep,    dim3(2184), dim3(256), 0, stream,
                     x, Wm, tt, ct, lng, lnb, Wq, bq, Wk, bk, xh, wht, wlt, ws);
  hipLaunchKernelGGL(stageB,  dim3(512),  dim3(256), 0, stream,
                     xh, wht, wlt, bm, ws);
  hipLaunchKernelGGL(stageC1, dim3(128),  dim3(256), 0, stream, ws);
  hipLaunchKernelGGL(stageC2, dim3(64),   dim3(256), 0, stream, ws, out);
}

// Round 8
// 112.111 us; speedup vs baseline: 1.0676x; 1.0676x over previous
//
#include <hip/hip_runtime.h>
#include <hip/hip_bf16.h>
#include <math.h>

#define BB 4
#define NN 2046
#define IND 512
#define DD 1024
#define SS 2048
#define MM (BB*NN)          // 8184 real rows, padded to 8192
#define MPAD 8192
#define RPAD 8256
#define EPSV 1e-5f

// ---- ws float offsets ----
#define F_U      0          // [2][1024] u-vectors
#define F_G      2048       // [32]
#define F_C2     2080       // [32]
#define F_SSPEC  2112       // [2][2] special-row s1,s2
#define F_DEN    2116       // [128] softmax denominators
#define F_S12    4096       // [8192][8 nb][2] per-ntile S1,S2 partials
#define F_A      135168     // [32][RPAD] A-values (specials at MPAD+p)
// ---- ws byte offsets ----
#define B_XH   1597440      // bf16[8192][512]   x hi
#define B_WHT  9986048      // bf16[1024][512]   W^T hi

typedef float f32x4 __attribute__((ext_vector_type(4)));
typedef __bf16 bf16x8 __attribute__((ext_vector_type(8)));
typedef unsigned short u16x8 __attribute__((ext_vector_type(8)));

__device__ __forceinline__ unsigned short f2bf_rne(float f) {
  unsigned int u = __float_as_uint(f);
  u += 0x7FFFu + ((u >> 16) & 1u);
  return (unsigned short)(u >> 16);
}
__device__ __forceinline__ float bf2f(unsigned short h) {
  return __uint_as_float(((unsigned int)h) << 16);
}
__device__ __forceinline__ float waveSum(float v) {
  #pragma unroll
  for (int m = 32; m >= 1; m >>= 1) v += __shfl_xor(v, m, 64);
  return v;
}
__device__ __forceinline__ float blockReduceSum(float v, volatile float* buf4) {
  #pragma unroll
  for (int m = 32; m >= 1; m >>= 1) v += __shfl_xor(v, m, 64);
  int wid = threadIdx.x >> 6;
  __syncthreads();
  if ((threadIdx.x & 63) == 0) buf4[wid] = v;
  __syncthreads();
  return buf4[0] + buf4[1] + buf4[2] + buf4[3];
}

#define GLOAD_LDS16(g, l) \
  __builtin_amdgcn_global_load_lds((const __attribute__((address_space(1))) void*)(g), \
                                   (__attribute__((address_space(3))) void*)(l), 16, 0, 0)

// ---------------------------------------------------------------------------
// prep: convX (x->xh bf16 hi, rows padded to 8192) | convW (W -> transposed
// hi bf16 [1024][512]) | stageA (LN consts, u, G, C2, special-row S/A)
// ---------------------------------------------------------------------------
__global__ __launch_bounds__(256) void prep(
    const float* __restrict__ x, const float* __restrict__ Wm,
    const float* __restrict__ tt, const float* __restrict__ ct,
    const float* __restrict__ lng, const float* __restrict__ lnb,
    const float* __restrict__ Wq, const float* __restrict__ bq,
    const float* __restrict__ Wk, const float* __restrict__ bk,
    unsigned short* __restrict__ xh, unsigned short* __restrict__ wht,
    float* __restrict__ ws) {
  __shared__ float tile[64][65];
  __shared__ float hq[4][64];
  __shared__ float qs[4][64];
  const int bid = blockIdx.x, t = threadIdx.x;

  if (bid < 2048) {                     // ---- convX ----
    const int row = bid * 4 + (t >> 6);
    const int c0 = (t & 63) * 8;
    const size_t po = (size_t)row * IND + c0;
    u16x8 hv;
    if (row < MM) {
      const float4* xv = (const float4*)(x + po);
      float4 a = xv[0], b = xv[1];
      float vv[8] = {a.x, a.y, a.z, a.w, b.x, b.y, b.z, b.w};
      #pragma unroll
      for (int i = 0; i < 8; ++i) hv[i] = f2bf_rne(vv[i]);
    } else {
      #pragma unroll
      for (int i = 0; i < 8; ++i) hv[i] = 0;
    }
    *(u16x8*)(xh + po) = hv;
  } else if (bid < 2176) {              // ---- convW: transpose + hi ----
    const int b2 = bid - 2048;
    const int kb = b2 >> 4, nb = b2 & 15;
    const int k0 = kb * 64, n0 = nb * 64;
    #pragma unroll
    for (int q = 0; q < 16; ++q) {
      int lin = q * 256 + t;
      int kk = lin >> 6, nn = lin & 63;
      tile[kk][nn] = Wm[(size_t)(k0 + kk) * DD + n0 + nn];
    }
    __syncthreads();
    #pragma unroll
    for (int q = 0; q < 16; ++q) {
      int lin = q * 256 + t;
      int nn = lin >> 6, kk = lin & 63;
      wht[(size_t)(n0 + nn) * IND + k0 + kk] = f2bf_rne(tile[kk][nn]);
    }
  } else {                              // ---- stageA: one (s,h) per wave ----
    const int w = t >> 6, e = t & 63;
    const int sh = (bid - 2176) * 4 + w;
    const int s = sh >> 4, h = sh & 15;
    const float* src = s ? ct : tt;

    float s1 = 0.f, s2 = 0.f;
    #pragma unroll
    for (int i = 0; i < 16; ++i) { float v = src[i*64 + e]; s1 += v; s2 += v*v; }
    s1 = waveSum(s1); s2 = waveSum(s2);
    if (h == 0 && e == 0) {
      ws[F_SSPEC + s*2 + 0] = s1;
      ws[F_SSPEC + s*2 + 1] = s2;
    }
    const float mu = s1 * (1.f/DD);
    const float var = s2 * (1.f/DD) - mu*mu;
    const float rstd = rsqrtf(var + EPSV);
    const int d0 = h * 64;
    hq[w][e] = (src[d0+e] - mu) * rstd * lng[d0+e] + lnb[d0+e];
    float qv = bq[d0+e];
    #pragma unroll 8
    for (int d = 0; d < 64; ++d) qv += hq[w][d] * Wq[(size_t)(d0+d)*64 + e];
    qs[w][e] = qv;
    float wt = 0.f;
    #pragma unroll 8
    for (int ee = 0; ee < 64; ++ee) wt += Wk[(size_t)(d0+e)*64 + ee] * qs[w][ee];
    wt *= 0.125f;
    const float c = waveSum(qs[w][e] * bk[d0+e]) * 0.125f;
    const float u = lng[d0+e] * wt;
    ws[F_U + s*DD + d0 + e] = u;
    const float G  = waveSum(lng[d0+e] * wt);
    const float C  = waveSum(lnb[d0+e] * wt);
    const float a0 = waveSum(tt[d0+e] * u);
    const float a1 = waveSum(ct[d0+e] * u);
    if (e == 0) {
      ws[F_G  + sh] = G;
      ws[F_C2 + sh] = C + c;
      ws[F_A + (size_t)sh*RPAD + MPAD + 0] = a0;
      ws[F_A + (size_t)sh*RPAD + MPAD + 1] = a1;
    }
  }
}

// ---------------------------------------------------------------------------
// stageB: token GEMM xh[8192][512] @ W^T hi (single-product bf16), 128x128
// tiles, BK=64 double-buffered global_load_lds with counted vmcnt(8).
// R7's proven fence skeleton: sched_barrier(0) pins every phase edge;
// lgkmcnt(0) drains ds_reads before the WAR barrier. Fused epilogue:
// per-row S1/S2 partials + per-(query,head) A, zero atomics.
// bid = nb*64 + mb (the 8 nb-tiles sharing an mb row-panel land on one XCD).
// ---------------------------------------------------------------------------
__global__ __launch_bounds__(256, 2) void stageB(
    const unsigned short* __restrict__ xh,
    const unsigned short* __restrict__ wht,
    const float* __restrict__ bmap, float* __restrict__ ws) {
  __shared__ char smem[65536];  // A: [2][128][64]bf16 @0; B: [2][128][64] @32768
  const int t = threadIdx.x, wave = t >> 6, lane = t & 63;
  const int lj = lane & 15, lg = lane >> 4;
  const int mb = blockIdx.x & 63, nb = blockIdx.x >> 6;
  const int m0 = mb * 128, n0 = nb * 128;
  const int wr = wave >> 1, wc = wave & 1;
  const float* U = ws + F_U;

  f32x4 acc[4][4];
  #pragma unroll
  for (int i = 0; i < 4; ++i)
    #pragma unroll
    for (int j = 0; j < 4; ++j) acc[i][j] = (f32x4){0.f,0.f,0.f,0.f};

  const int srow = lane >> 3;                 // 0..7: row within 8-row group
  const int gslot = (lane & 7) ^ srow;        // pre-swizzled global 16B slot

  #define STAGE(ks, buf) do {                                                  \
    const size_t ko_ = (size_t)(ks)*64 + gslot*8;                              \
    _Pragma("unroll")                                                          \
    for (int q = 0; q < 4; ++q) {                                              \
      const int rb = wave*32 + q*8;                                            \
      GLOAD_LDS16(xh  + (size_t)(m0 + rb + srow)*IND + ko_,                    \
                  smem + (buf)*16384 + rb*128);                                \
      GLOAD_LDS16(wht + (size_t)(n0 + rb + srow)*IND + ko_,                    \
                  smem + 32768 + (buf)*16384 + rb*128);                        \
    }                                                                          \
  } while (0)

  STAGE(0, 0);
  #pragma unroll
  for (int k = 0; k < 8; ++k) {
    if (k < 7) {
      STAGE(k + 1, (k + 1) & 1);
      asm volatile("s_waitcnt vmcnt(8)" ::: "memory");
    } else {
      asm volatile("s_waitcnt vmcnt(0)" ::: "memory");
    }
    __builtin_amdgcn_sched_barrier(0);
    __builtin_amdgcn_s_barrier();
    __builtin_amdgcn_sched_barrier(0);
    #pragma unroll
    for (int kf = 0; kf < 2; ++kf) {
      const int ab = (k & 1) * 16384;
      const int bb = 32768 + (k & 1) * 16384;
      const int sl = kf*4 + lg;
      bf16x8 af[4], bfh[4];
      #pragma unroll
      for (int i = 0; i < 4; ++i) {
        const int r = wr*64 + i*16 + lj;
        af[i] = *(const bf16x8*)(smem + ab + r*128 + ((sl ^ (r & 7)) * 16));
      }
      #pragma unroll
      for (int j = 0; j < 4; ++j) {
        const int r = wc*64 + j*16 + lj;
        bfh[j] = *(const bf16x8*)(smem + bb + r*128 + ((sl ^ (r & 7)) * 16));
      }
      #pragma unroll
      for (int i = 0; i < 4; ++i)
        #pragma unroll
        for (int j = 0; j < 4; ++j)
          acc[i][j] = __builtin_amdgcn_mfma_f32_16x16x32_bf16(af[i], bfh[j], acc[i][j], 0,0,0);
    }
    __builtin_amdgcn_sched_barrier(0);
    asm volatile("s_waitcnt lgkmcnt(0)" ::: "memory");
    __builtin_amdgcn_sched_barrier(0);
    __builtin_amdgcn_s_barrier();
    __builtin_amdgcn_sched_barrier(0);
  }
  #undef STAGE

  // ---- fused epilogue: per-row S1,S2 and per-(query,head) A ----
  float s1p[16], s2p[16], a0p[16], a1p[16];
  #pragma unroll
  for (int p = 0; p < 16; ++p) { s1p[p]=0.f; s2p[p]=0.f; a0p[p]=0.f; a1p[p]=0.f; }
  #pragma unroll
  for (int j = 0; j < 4; ++j) {
    const int gc = n0 + wc*64 + j*16 + lj;
    const float bmv = bmap[gc];
    const float u0 = U[gc], u1 = U[DD + gc];
    #pragma unroll
    for (int i = 0; i < 4; ++i)
      #pragma unroll
      for (int r = 0; r < 4; ++r) {
        const float tok = acc[i][j][r] + bmv;
        const int p = i*4 + r;
        s1p[p] += tok; s2p[p] += tok*tok;
        a0p[p] += tok*u0; a1p[p] += tok*u1;
      }
  }
  #pragma unroll
  for (int msk = 8; msk >= 1; msk >>= 1)
    #pragma unroll
    for (int p = 0; p < 16; ++p) {
      s1p[p] += __shfl_xor(s1p[p], msk, 64);
      s2p[p] += __shfl_xor(s2p[p], msk, 64);
      a0p[p] += __shfl_xor(a0p[p], msk, 64);
      a1p[p] += __shfl_xor(a1p[p], msk, 64);
    }

  if (lj == 0) {
    const int h = nb*2 + wc;            // head owned by this wave's col-half
    #pragma unroll
    for (int p = 0; p < 16; ++p) {
      const int row = m0 + wr*64 + (p>>2)*16 + lg*4 + (p&3);
      ws[F_A + (size_t)h*RPAD + row]        = a0p[p];
      ws[F_A + (size_t)(16 + h)*RPAD + row] = a1p[p];
    }
  }

  float* s12w = (float*)smem;           // reuse staging LDS: [4][64][2]
  if (lj == 0) {
    #pragma unroll
    for (int p = 0; p < 16; ++p) {
      const int rl = (p>>2)*16 + lg*4 + (p&3);
      s12w[(wave*64 + rl)*2 + 0] = s1p[p];
      s12w[(wave*64 + rl)*2 + 1] = s2p[p];
    }
  }
  __syncthreads();
  if (t < 128) {
    const int wv = t >> 6, rl = t & 63;
    const float s1 = s12w[((wv*2)*64 + rl)*2]     + s12w[((wv*2+1)*64 + rl)*2];
    const float s2 = s12w[((wv*2)*64 + rl)*2 + 1] + s12w[((wv*2+1)*64 + rl)*2 + 1];
    ws[F_S12 + (size_t)(m0 + t)*16 + nb*2 + 0] = s1;
    ws[F_S12 + (size_t)(m0 + t)*16 + nb*2 + 1] = s2;
  }
}

// ---------------------------------------------------------------------------
// moments: sum the 8 per-ntile partials (regular rows); specials from SSPEC
// ---------------------------------------------------------------------------
__device__ __forceinline__ void rowMoments(const float* __restrict__ ws, int p,
                                           int r, float& mu, float& rstd) {
  float s1, s2;
  if (p < 2) {
    s1 = ws[F_SSPEC + p*2 + 0];
    s2 = ws[F_SSPEC + p*2 + 1];
  } else {
    const float4* q4 = (const float4*)(ws + F_S12 + (size_t)r*16);
    const float4 a = q4[0], b = q4[1], c = q4[2], d = q4[3];
    s1 = (a.x + a.z) + (b.x + b.z) + (c.x + c.z) + (d.x + d.z);
    s2 = (a.y + a.w) + (b.y + b.w) + (c.y + c.w) + (d.y + d.w);
  }
  mu = s1 * (1.f/DD);
  const float var = s2 * (1.f/DD) - mu*mu;
  rstd = rsqrtf(var + EPSV);
}

// ---------------------------------------------------------------------------
// stageC1: per (b,s,h) softmax denominator
// ---------------------------------------------------------------------------
__global__ __launch_bounds__(256) void stageC1(float* __restrict__ ws) {
  __shared__ float rbuf[4];
  const int bid = blockIdx.x;           // b*32 + s*16 + h
  const int b = bid >> 5, sh = bid & 31;
  const int t = threadIdx.x;
  const float Gh = ws[F_G + sh], Ch = ws[F_C2 + sh];
  const float* Af = ws + F_A + (size_t)sh*RPAD;

  float sum = 0.f;
  #pragma unroll
  for (int i = 0; i < 8; ++i) {
    const int p = i*256 + t;
    const int r = (p < 2) ? (MPAD + p) : (b*NN + p - 2);
    float mu, rstd;
    rowMoments(ws, p, r, mu, rstd);
    const float sc = fminf(rstd*(Af[r] - mu*Gh) + Ch, 60.f);
    sum += __expf(sc);
  }
  sum = blockReduceSum(sum, rbuf);
  if (t == 0) ws[F_DEN + bid] = sum;
}

// ---------------------------------------------------------------------------
// stageC2: output = mean over heads of per-head softmax probs
// ---------------------------------------------------------------------------
__global__ __launch_bounds__(256) void stageC2(const float* __restrict__ ws,
                                               float* __restrict__ out) {
  __shared__ float dn[16], Gs[16], Cs[16];
  const int bid = blockIdx.x;           // (b*2+s)*8 + chunk
  const int bs = bid >> 3, chunk = bid & 7;
  const int b = bs >> 1, s = bs & 1;
  const int t = threadIdx.x;
  if (t < 16) {
    dn[t] = 1.f / ws[F_DEN + b*32 + s*16 + t];
    Gs[t] = ws[F_G  + s*16 + t];
    Cs[t] = ws[F_C2 + s*16 + t];
  }
  __syncthreads();
  const int p = chunk*256 + t;
  const int r = (p < 2) ? (MPAD + p) : (b*NN + p - 2);
  float mu, rstd;
  rowMoments(ws, p, r, mu, rstd);
  float acc = 0.f;
  #pragma unroll
  for (int h = 0; h < 16; ++h) {
    const float a = ws[F_A + (size_t)(s*16 + h)*RPAD + r];
    const float sc = fminf(rstd*(a - mu*Gs[h]) + Cs[h], 60.f);
    acc += __expf(sc) * dn[h];
  }
  out[(size_t)s*(BB*SS) + (size_t)b*SS + p] = acc * (1.f/16.f);
}

extern "C" void kernel_launch(void* const* d_in, const int* in_sizes, int n_in,
                              void* d_out, int out_size, void* d_ws, size_t ws_size,
                              hipStream_t stream) {
  const float* x   = (const float*)d_in[0];
  const float* Wm  = (const float*)d_in[1];
  const float* bm  = (const float*)d_in[2];
  const float* tt  = (const float*)d_in[3];
  const float* ct  = (const float*)d_in[4];
  const float* lng = (const float*)d_in[5];
  const float* lnb = (const float*)d_in[6];
  const float* Wq  = (const float*)d_in[7];
  const float* bq  = (const float*)d_in[8];
  const float* Wk  = (const float*)d_in[9];
  const float* bk  = (const float*)d_in[10];
  char* wsb = (char*)d_ws;
  float* ws = (float*)d_ws;
  float* out = (float*)d_out;

  unsigned short* xh  = (unsigned short*)(wsb + B_XH);
  unsigned short* wht = (unsigned short*)(wsb + B_WHT);

  hipLaunchKernelGGL(prep,    dim3(2184), dim3(256), 0, stream,
                     x, Wm, tt, ct, lng, lnb, Wq, bq, Wk, bk, xh, wht, ws);
  hipLaunchKernelGGL(stageB,  dim3(512),  dim3(256), 0, stream,
                     xh, wht, bm, ws);
  hipLaunchKernelGGL(stageC1, dim3(128),  dim3(256), 0, stream, ws);
  hipLaunchKernelGGL(stageC2, dim3(64),   dim3(256), 0, stream, ws, out);
}